// Round 1
// baseline (444.307 us; speedup 1.0000x reference)
//
#include <hip/hip_runtime.h>
#include <math.h>
#include <stdint.h>

#define NTOK   16384
#define DIM    4096
#define NEXP   256
#define TOPKG  4
#define TOPK   8
#define NSPLIT 4
#define KCHUNK (DIM / NSPLIT)   // 1024
#define BM     256              // tokens per block (was 128)
#define BK     32
#define NSTEPS (KCHUNK / BK)    // 32

typedef float v4f   __attribute__((ext_vector_type(4)));
typedef short short8 __attribute__((ext_vector_type(8)));

__device__ inline unsigned short f2bf(float x) {           // round-to-nearest-even
    unsigned u = __float_as_uint(x);
    return (unsigned short)((u + 0x7fffu + ((u >> 16) & 1u)) >> 16);
}
__device__ inline float bf2f(unsigned short h) {
    return __uint_as_float(((unsigned)h) << 16);
}

// ---- W fp32 -> bf16 (hi, lo) row-major [256][4096], done once per call ----
__global__ __launch_bounds__(256) void wprep(const float* __restrict__ W,
                                             unsigned short* __restrict__ Wh,
                                             unsigned short* __restrict__ Wl) {
    int i = (blockIdx.x * 256 + threadIdx.x) * 4;
    float4 v = *(const float4*)(W + i);
    ushort4 h, l;
    h.x = f2bf(v.x); l.x = f2bf(v.x - bf2f(h.x));
    h.y = f2bf(v.y); l.y = f2bf(v.y - bf2f(h.y));
    h.z = f2bf(v.z); l.z = f2bf(v.z - bf2f(h.z));
    h.w = f2bf(v.w); l.w = f2bf(v.w - bf2f(h.w));
    *(ushort4*)(Wh + i) = h;
    *(ushort4*)(Wl + i) = l;
}

// ---- GEMM: P[z][t][e] = sum_{k in chunk z} X[t,k] W[e,k], bf16x2 3-pass MFMA ----
// 2-phase pipelined: BM=256, 512 thr (8 waves, 2x4 wave grid), dbuf LDS 128 KiB,
// ONE barrier per K-step. Prefetch tile t+1 (A->regs, B->global_load_lds) is
// issued BEFORE the 96-MFMA compute phase, so the end-of-step vmcnt(0)+barrier
// drain is covered by ~3.7k cycles of MFMA. Grid (64,4)=256 blocks = 1/CU.
__global__ __launch_bounds__(512, 2) void gate_gemm(const float* __restrict__ X,
                                                    const unsigned short* __restrict__ Wh,
                                                    const unsigned short* __restrict__ Wl,
                                                    float* __restrict__ P) {
    __shared__ __align__(16) unsigned short Ah[2][BM * BK];    // 2 x 16 KiB
    __shared__ __align__(16) unsigned short Al[2][BM * BK];    // 2 x 16 KiB
    __shared__ __align__(16) unsigned short Bh[2][NEXP * BK];  // 2 x 16 KiB
    __shared__ __align__(16) unsigned short Bl[2][NEXP * BK];  // 2 x 16 KiB

    const int t  = threadIdx.x;            // 0..511
    const int bm = blockIdx.x * BM;
    const int z  = blockIdx.y;
    const int k0 = z * KCHUNK;

    const int l  = t & 63;
    const int w  = t >> 6;                 // 0..7
    const int wr = w >> 2;                 // 0..1: row half (128 tokens)
    const int wc = w & 3;                  // 0..3: col quarter (64 experts)
    const int lm = l & 15;                 // m/n within 16x16 tile
    const int lq = l >> 4;                 // k-quad (0..3)

    // A staging: thread t -> row t>>1 (0..255), k-half (t&1)*16
    const int ar = t >> 1;
    const int ak = (t & 1) * 16;
    const float* xrow = X + (size_t)(bm + ar) * DIM + k0 + ak;

    v4f acc[8][4] = {};

    // ---- prologue: stage tile 0 into buffer 0 ----
    {
#pragma unroll
        for (int i = 0; i < 2; ++i) {
            int flat = i * 512 + t;          // 0..1023
            int e = flat >> 2, q = flat & 3; // row, 16B-quarter of 64B row
            const unsigned short* gh = Wh + (size_t)e * DIM + k0 + q * 8;
            const unsigned short* gl = Wl + (size_t)e * DIM + k0 + q * 8;
            __builtin_amdgcn_global_load_lds(
                (const __attribute__((address_space(1))) unsigned int*)gh,
                (__attribute__((address_space(3))) unsigned int*)&Bh[0][flat * 8], 16, 0, 0);
            __builtin_amdgcn_global_load_lds(
                (const __attribute__((address_space(1))) unsigned int*)gl,
                (__attribute__((address_space(3))) unsigned int*)&Bl[0][flat * 8], 16, 0, 0);
        }
        float4 xv[4];
#pragma unroll
        for (int i = 0; i < 4; ++i) xv[i] = *(const float4*)(xrow + i * 4);
#pragma unroll
        for (int i = 0; i < 4; ++i) {
            ushort4 h, lo;
            h.x = f2bf(xv[i].x); lo.x = f2bf(xv[i].x - bf2f(h.x));
            h.y = f2bf(xv[i].y); lo.y = f2bf(xv[i].y - bf2f(h.y));
            h.z = f2bf(xv[i].z); lo.z = f2bf(xv[i].z - bf2f(h.z));
            h.w = f2bf(xv[i].w); lo.w = f2bf(xv[i].w - bf2f(h.w));
            *(ushort4*)&Ah[0][ar * BK + ak + i * 4] = h;
            *(ushort4*)&Al[0][ar * BK + ak + i * 4] = lo;
        }
        __syncthreads();   // drains vmcnt(0)+lgkmcnt(0): tile 0 visible
    }

    int p = 0;
    for (int s = 0; s < NSTEPS; ++s) {
        // prefetch K-offset (clamped on last step: harmless redundant restage)
        const int krn = (s + 1 < NSTEPS ? s + 1 : s) * BK;

        // ---- issue prefetch of tile s+1 (no waits here) ----
        float4 xv[4];
#pragma unroll
        for (int i = 0; i < 4; ++i) xv[i] = *(const float4*)(xrow + krn + i * 4);
#pragma unroll
        for (int i = 0; i < 2; ++i) {
            int flat = i * 512 + t;
            int e = flat >> 2, q = flat & 3;
            const unsigned short* gh = Wh + (size_t)e * DIM + k0 + krn + q * 8;
            const unsigned short* gl = Wl + (size_t)e * DIM + k0 + krn + q * 8;
            __builtin_amdgcn_global_load_lds(
                (const __attribute__((address_space(1))) unsigned int*)gh,
                (__attribute__((address_space(3))) unsigned int*)&Bh[p ^ 1][flat * 8], 16, 0, 0);
            __builtin_amdgcn_global_load_lds(
                (const __attribute__((address_space(1))) unsigned int*)gl,
                (__attribute__((address_space(3))) unsigned int*)&Bl[p ^ 1][flat * 8], 16, 0, 0);
        }

        // ---- compute tile s from buffer p ----
        short8 bh[4], bl[4];
#pragma unroll
        for (int c = 0; c < 4; ++c) {
            int e = wc * 64 + c * 16 + lm;
            bh[c] = *(const short8*)&Bh[p][e * BK + lq * 8];
            bl[c] = *(const short8*)&Bl[p][e * BK + lq * 8];
        }
#pragma unroll
        for (int r = 0; r < 8; ++r) {
            int m = wr * 128 + r * 16 + lm;
            short8 ah = *(const short8*)&Ah[p][m * BK + lq * 8];
            short8 al = *(const short8*)&Al[p][m * BK + lq * 8];
#pragma unroll
            for (int c = 0; c < 4; ++c) {
                acc[r][c] = __builtin_amdgcn_mfma_f32_16x16x32_bf16(ah, bh[c], acc[r][c], 0, 0, 0);
                acc[r][c] = __builtin_amdgcn_mfma_f32_16x16x32_bf16(ah, bl[c], acc[r][c], 0, 0, 0);
                acc[r][c] = __builtin_amdgcn_mfma_f32_16x16x32_bf16(al, bh[c], acc[r][c], 0, 0, 0);
            }
        }

        // keep the xv-dependent convert (and its vmcnt wait) BELOW the MFMAs
        __builtin_amdgcn_sched_barrier(0);

        // ---- convert + write A(s+1) into buffer p^1 ----
#pragma unroll
        for (int i = 0; i < 4; ++i) {
            ushort4 h, lo;
            h.x = f2bf(xv[i].x); lo.x = f2bf(xv[i].x - bf2f(h.x));
            h.y = f2bf(xv[i].y); lo.y = f2bf(xv[i].y - bf2f(h.y));
            h.z = f2bf(xv[i].z); lo.z = f2bf(xv[i].z - bf2f(h.z));
            h.w = f2bf(xv[i].w); lo.w = f2bf(xv[i].w - bf2f(h.w));
            *(ushort4*)&Ah[p ^ 1][ar * BK + ak + i * 4] = h;
            *(ushort4*)&Al[p ^ 1][ar * BK + ak + i * 4] = lo;
        }

        __syncthreads();   // single barrier/step: drains B gl_lds + A ds_writes
        p ^= 1;
    }

    // epilogue: C/D layout col=lane&15, row=lq*4+reg (verified m89/m91)
    float* Pb = P + ((size_t)z * NTOK + bm) * NEXP;
#pragma unroll
    for (int r = 0; r < 8; ++r)
#pragma unroll
        for (int c = 0; c < 4; ++c)
#pragma unroll
            for (int g = 0; g < 4; ++g)
                Pb[(size_t)(wr * 128 + r * 16 + lq * 4 + g) * NEXP + wc * 64 + c * 16 + lm] = acc[r][c][g];
}

// ---- fused reduce (4 partials, fixed order) + routing: one wave per token ----
__global__ __launch_bounds__(256) void gate_route(const float* __restrict__ P,
                                                  float* __restrict__ outw,
                                                  float* __restrict__ outi) {
    const int lane = threadIdx.x & 63;
    const int tok  = (blockIdx.x * blockDim.x + threadIdx.x) >> 6;
    if (tok >= NTOK) return;

    float l[4] = {0.f, 0.f, 0.f, 0.f};
#pragma unroll
    for (int z = 0; z < NSPLIT; ++z) {   // fixed order: deterministic across runs
        float4 v = *(const float4*)(P + ((size_t)z * NTOK + tok) * NEXP + lane * 4);
        l[0] += v.x; l[1] += v.y; l[2] += v.z; l[3] += v.w;
    }

    float lmax = fmaxf(fmaxf(l[0], l[1]), fmaxf(l[2], l[3]));
    float m = lmax;
#pragma unroll
    for (int o = 32; o; o >>= 1) m = fmaxf(m, __shfl_xor(m, o));

    float s = __expf(l[0] - m) + __expf(l[1] - m) + __expf(l[2] - m) + __expf(l[3] - m);
#pragma unroll
    for (int o = 32; o; o >>= 1) s += __shfl_xor(s, o);

    float gm = lmax;
#pragma unroll
    for (int o = 4; o; o >>= 1) gm = fmaxf(gm, __shfl_xor(gm, o));

    const int g = lane >> 3;
    int rank = 0;
#pragma unroll
    for (int gg = 0; gg < 8; ++gg) {
        float vg = __shfl(gm, gg * 8);
        rank += (vg > gm) || (vg == gm && gg < g);
    }
    const bool allowed = rank < TOPKG;

    float mv[4];
#pragma unroll
    for (int j = 0; j < 4; ++j) mv[j] = allowed ? l[j] : -INFINITY;

    float wsel = 0.0f;
    int   isel = 0;

    for (int k = 0; k < TOPK; ++k) {
        float bv = mv[0];
        int   bi = lane * 4;
        if (mv[1] > bv) { bv = mv[1]; bi = lane * 4 + 1; }
        if (mv[2] > bv) { bv = mv[2]; bi = lane * 4 + 2; }
        if (mv[3] > bv) { bv = mv[3]; bi = lane * 4 + 3; }
#pragma unroll
        for (int o = 32; o; o >>= 1) {
            float ov = __shfl_xor(bv, o);
            int   oi = __shfl_xor(bi, o);
            if (ov > bv || (ov == bv && oi < bi)) { bv = ov; bi = oi; }
        }
        if (lane == k) { wsel = __expf(bv - m) / s; isel = bi; }
        if ((bi >> 2) == lane) mv[bi & 3] = -INFINITY;
    }

    if (lane < TOPK) {
        outw[(size_t)tok * TOPK + lane] = wsel;
        outi[(size_t)tok * TOPK + lane] = (float)isel;
    }
}

extern "C" void kernel_launch(void* const* d_in, const int* in_sizes, int n_in,
                              void* d_out, int out_size, void* d_ws, size_t ws_size,
                              hipStream_t stream) {
    const float* x  = (const float*)d_in[0];   // [16384, 4096]
    const float* wt = (const float*)d_in[1];   // [256, 4096]

    // ws layout: partials [4][16384][256] f32 (64 MB) | Wh (2 MB) | Wl (2 MB)
    float* P = (float*)d_ws;
    unsigned short* Wh = (unsigned short*)((char*)d_ws + (size_t)NSPLIT * NTOK * NEXP * 4);
    unsigned short* Wl = Wh + (size_t)NEXP * DIM;

    float* outw = (float*)d_out;
    float* outi = (float*)d_out + (size_t)NTOK * TOPK;

    wprep<<<(NEXP * DIM) / (256 * 4), 256, 0, stream>>>(wt, Wh, Wl);

    dim3 ggrid(NTOK / BM, NSPLIT);   // (64, 4) = 256 blocks, 1/CU, 8 waves
    gate_gemm<<<ggrid, 512, 0, stream>>>(x, Wh, Wl, P);

    gate_route<<<(NTOK * 64) / 256, 256, 0, stream>>>(P, outw, outi);
}

// Round 2
// 438.607 us; speedup vs baseline: 1.0130x; 1.0130x over previous
//
#include <hip/hip_runtime.h>
#include <math.h>
#include <stdint.h>

#define NTOK   16384
#define DIM    4096
#define NEXP   256
#define TOPKG  4
#define TOPK   8
#define NSPLIT 4
#define KCHUNK (DIM / NSPLIT)   // 1024
#define BM     256
#define BK     32
#define NSTEPS (KCHUNK / BK)    // 32

typedef float v4f   __attribute__((ext_vector_type(4)));
typedef short short8 __attribute__((ext_vector_type(8)));

__device__ inline unsigned short f2bf(float x) {           // round-to-nearest-even
    unsigned u = __float_as_uint(x);
    return (unsigned short)((u + 0x7fffu + ((u >> 16) & 1u)) >> 16);
}
__device__ inline float bf2f(unsigned short h) {
    return __uint_as_float(((unsigned)h) << 16);
}
// 4-slot XOR swizzle within a 64B row: spreads 16-consecutive-row b128 reads
// across all bank groups (2-way residual = free per m136).
__device__ inline int swz4(int row, int slot) { return slot ^ ((row >> 1) & 3); }

// ---- W fp32 -> bf16 (hi, lo) row-major [256][4096], done once per call ----
__global__ __launch_bounds__(256) void wprep(const float* __restrict__ W,
                                             unsigned short* __restrict__ Wh,
                                             unsigned short* __restrict__ Wl) {
    int i = (blockIdx.x * 256 + threadIdx.x) * 4;
    float4 v = *(const float4*)(W + i);
    ushort4 h, l;
    h.x = f2bf(v.x); l.x = f2bf(v.x - bf2f(h.x));
    h.y = f2bf(v.y); l.y = f2bf(v.y - bf2f(h.y));
    h.z = f2bf(v.z); l.z = f2bf(v.z - bf2f(h.z));
    h.w = f2bf(v.w); l.w = f2bf(v.w - bf2f(h.w));
    *(ushort4*)(Wh + i) = h;
    *(ushort4*)(Wl + i) = l;
}

// ---- GEMM: P[z][t][e] = sum_{k in chunk z} X[t,k] W[e,k], bf16x2 3-pass MFMA ----
// 8-phase-style schedule (T3+T4) + LDS XOR swizzle (T2) + setprio (T5):
// per K-step 4 phases, each {ds_read 2-row quadrant | 1 staging piece |
// s_barrier | lgkmcnt(0) | 24 MFMA | s_barrier}. Staging for s+1 spread over
// P0..P3; ONLY the step-final barrier is __syncthreads() (full drain =
// publish). B staged via global_load_lds with PRE-SWIZZLED SOURCE + linear
// dest (rule #21); A staged reg->convert->swizzled ds_write.
__global__ __launch_bounds__(512, 2) void gate_gemm(const float* __restrict__ X,
                                                    const unsigned short* __restrict__ Wh,
                                                    const unsigned short* __restrict__ Wl,
                                                    float* __restrict__ P) {
    __shared__ __align__(16) unsigned short Ah[2][BM * BK];    // 2 x 16 KiB
    __shared__ __align__(16) unsigned short Al[2][BM * BK];
    __shared__ __align__(16) unsigned short Bh[2][NEXP * BK];
    __shared__ __align__(16) unsigned short Bl[2][NEXP * BK];  // total 128 KiB

    const int t  = threadIdx.x;            // 0..511
    const int bm = blockIdx.x * BM;
    const int z  = blockIdx.y;
    const int k0 = z * KCHUNK;

    const int l  = t & 63;
    const int w  = t >> 6;                 // 0..7
    const int wr = w >> 2;                 // 0..1: row half (128 tokens)
    const int wc = w & 3;                  // 0..3: col quarter (64 experts)
    const int lm = l & 15;
    const int lq = l >> 4;                 // 16B slot (0..3)

    // A staging: thread t -> row t>>1 (0..255), k-half (t&1)*16
    const int ar = t >> 1;
    const float* xrow = X + (size_t)(bm + ar) * DIM + k0 + (t & 1) * 16;

    v4f acc[8][4] = {};

    // ---- prologue: stage tile 0 into buffer 0 ----
    {
#pragma unroll
        for (int i = 0; i < 2; ++i) {
            int flat = i * 512 + t;
            int e = flat >> 2, qq = flat & 3;
            const unsigned short* gh = Wh + (size_t)e * DIM + k0 + swz4(e, qq) * 8;
            const unsigned short* gl = Wl + (size_t)e * DIM + k0 + swz4(e, qq) * 8;
            __builtin_amdgcn_global_load_lds(
                (const __attribute__((address_space(1))) unsigned int*)gh,
                (__attribute__((address_space(3))) unsigned int*)&Bh[0][flat * 8], 16, 0, 0);
            __builtin_amdgcn_global_load_lds(
                (const __attribute__((address_space(1))) unsigned int*)gl,
                (__attribute__((address_space(3))) unsigned int*)&Bl[0][flat * 8], 16, 0, 0);
        }
        float4 xv0[4];
#pragma unroll
        for (int i = 0; i < 4; ++i) xv0[i] = *(const float4*)(xrow + i * 4);
#pragma unroll
        for (int i = 0; i < 4; ++i) {
            ushort4 h, lo;
            h.x = f2bf(xv0[i].x); lo.x = f2bf(xv0[i].x - bf2f(h.x));
            h.y = f2bf(xv0[i].y); lo.y = f2bf(xv0[i].y - bf2f(h.y));
            h.z = f2bf(xv0[i].z); lo.z = f2bf(xv0[i].z - bf2f(h.z));
            h.w = f2bf(xv0[i].w); lo.w = f2bf(xv0[i].w - bf2f(h.w));
            int j = (t & 1) * 4 + i;
            int idx = ar * BK + swz4(ar, j >> 1) * 8 + (j & 1) * 4;
            *(ushort4*)&Ah[0][idx] = h;
            *(ushort4*)&Al[0][idx] = lo;
        }
        __syncthreads();   // full drain: tile 0 visible
    }

    int cur = 0;
    for (int s = 0; s < NSTEPS; ++s) {
        const int nxt = cur ^ 1;
        const bool pf = (s + 1 < NSTEPS);
        const int krn = (pf ? s + 1 : s) * BK;

        short8 bh[4], bl[4];
        float4 xv[4];

#pragma unroll
        for (int q = 0; q < 4; ++q) {
            // ---- ds_reads for this phase (buffer cur) ----
            if (q == 0) {
#pragma unroll
                for (int c = 0; c < 4; ++c) {
                    int e = wc * 64 + c * 16 + lm;
                    bh[c] = *(const short8*)&Bh[cur][e * BK + swz4(e, lq) * 8];
                    bl[c] = *(const short8*)&Bl[cur][e * BK + swz4(e, lq) * 8];
                }
            }
            const int m0 = wr * 128 + (2 * q) * 16 + lm;
            const int m1 = m0 + 16;
            short8 a0h = *(const short8*)&Ah[cur][m0 * BK + swz4(m0, lq) * 8];
            short8 a0l = *(const short8*)&Al[cur][m0 * BK + swz4(m0, lq) * 8];
            short8 a1h = *(const short8*)&Ah[cur][m1 * BK + swz4(m1, lq) * 8];
            short8 a1l = *(const short8*)&Al[cur][m1 * BK + swz4(m1, lq) * 8];

            // ---- one staging piece for step s+1 (buffer nxt) ----
            if (pf) {
                if (q == 0) {
#pragma unroll
                    for (int i = 0; i < 4; ++i) xv[i] = *(const float4*)(xrow + krn + i * 4);
#pragma unroll
                    for (int i = 0; i < 2; ++i) {
                        int flat = i * 512 + t;
                        int e = flat >> 2, qq = flat & 3;
                        const unsigned short* g = Wh + (size_t)e * DIM + k0 + krn + swz4(e, qq) * 8;
                        __builtin_amdgcn_global_load_lds(
                            (const __attribute__((address_space(1))) unsigned int*)g,
                            (__attribute__((address_space(3))) unsigned int*)&Bh[nxt][flat * 8], 16, 0, 0);
                    }
                } else if (q == 1) {
#pragma unroll
                    for (int i = 0; i < 2; ++i) {
                        int flat = i * 512 + t;
                        int e = flat >> 2, qq = flat & 3;
                        const unsigned short* g = Wl + (size_t)e * DIM + k0 + krn + swz4(e, qq) * 8;
                        __builtin_amdgcn_global_load_lds(
                            (const __attribute__((address_space(1))) unsigned int*)g,
                            (__attribute__((address_space(3))) unsigned int*)&Bl[nxt][flat * 8], 16, 0, 0);
                    }
                } else {
                    const int i0 = (q == 2) ? 0 : 2;   // convert half per phase
#pragma unroll
                    for (int i = i0; i < i0 + 2; ++i) {
                        ushort4 h, lo;
                        h.x = f2bf(xv[i].x); lo.x = f2bf(xv[i].x - bf2f(h.x));
                        h.y = f2bf(xv[i].y); lo.y = f2bf(xv[i].y - bf2f(h.y));
                        h.z = f2bf(xv[i].z); lo.z = f2bf(xv[i].z - bf2f(h.z));
                        h.w = f2bf(xv[i].w); lo.w = f2bf(xv[i].w - bf2f(h.w));
                        int j = (t & 1) * 4 + i;
                        int idx = ar * BK + swz4(ar, j >> 1) * 8 + (j & 1) * 4;
                        *(ushort4*)&Ah[nxt][idx] = h;
                        *(ushort4*)&Al[nxt][idx] = lo;
                    }
                }
            }

            if (q == 0) asm volatile("s_waitcnt lgkmcnt(8)");   // 12 reads issued
            __builtin_amdgcn_s_barrier();
            asm volatile("s_waitcnt lgkmcnt(0)");
            __builtin_amdgcn_sched_barrier(0);                  // rule #18
            __builtin_amdgcn_s_setprio(1);
#pragma unroll
            for (int c = 0; c < 4; ++c) {
                acc[2 * q][c] = __builtin_amdgcn_mfma_f32_16x16x32_bf16(a0h, bh[c], acc[2 * q][c], 0, 0, 0);
                acc[2 * q][c] = __builtin_amdgcn_mfma_f32_16x16x32_bf16(a0h, bl[c], acc[2 * q][c], 0, 0, 0);
                acc[2 * q][c] = __builtin_amdgcn_mfma_f32_16x16x32_bf16(a0l, bh[c], acc[2 * q][c], 0, 0, 0);
            }
#pragma unroll
            for (int c = 0; c < 4; ++c) {
                acc[2 * q + 1][c] = __builtin_amdgcn_mfma_f32_16x16x32_bf16(a1h, bh[c], acc[2 * q + 1][c], 0, 0, 0);
                acc[2 * q + 1][c] = __builtin_amdgcn_mfma_f32_16x16x32_bf16(a1h, bl[c], acc[2 * q + 1][c], 0, 0, 0);
                acc[2 * q + 1][c] = __builtin_amdgcn_mfma_f32_16x16x32_bf16(a1l, bh[c], acc[2 * q + 1][c], 0, 0, 0);
            }
            __builtin_amdgcn_s_setprio(0);
            if (q < 3) __builtin_amdgcn_s_barrier();
            else       __syncthreads();   // ONE full drain/step: publishes nxt
        }
        cur = nxt;
    }

    // epilogue: C/D layout col=lane&15, row=lq*4+reg (verified m89/m91)
    float* Pb = P + ((size_t)z * NTOK + bm) * NEXP;
#pragma unroll
    for (int r = 0; r < 8; ++r)
#pragma unroll
        for (int c = 0; c < 4; ++c)
#pragma unroll
            for (int g = 0; g < 4; ++g)
                Pb[(size_t)(wr * 128 + r * 16 + lq * 4 + g) * NEXP + wc * 64 + c * 16 + lm] = acc[r][c][g];
}

// ---- fused reduce (4 partials, fixed order) + routing: one wave per token ----
__global__ __launch_bounds__(256) void gate_route(const float* __restrict__ P,
                                                  float* __restrict__ outw,
                                                  float* __restrict__ outi) {
    const int lane = threadIdx.x & 63;
    const int tok  = (blockIdx.x * blockDim.x + threadIdx.x) >> 6;
    if (tok >= NTOK) return;

    float l[4] = {0.f, 0.f, 0.f, 0.f};
#pragma unroll
    for (int z = 0; z < NSPLIT; ++z) {   // fixed order: deterministic across runs
        float4 v = *(const float4*)(P + ((size_t)z * NTOK + tok) * NEXP + lane * 4);
        l[0] += v.x; l[1] += v.y; l[2] += v.z; l[3] += v.w;
    }

    float lmax = fmaxf(fmaxf(l[0], l[1]), fmaxf(l[2], l[3]));
    float m = lmax;
#pragma unroll
    for (int o = 32; o; o >>= 1) m = fmaxf(m, __shfl_xor(m, o));

    float s = __expf(l[0] - m) + __expf(l[1] - m) + __expf(l[2] - m) + __expf(l[3] - m);
#pragma unroll
    for (int o = 32; o; o >>= 1) s += __shfl_xor(s, o);

    float gm = lmax;
#pragma unroll
    for (int o = 4; o; o >>= 1) gm = fmaxf(gm, __shfl_xor(gm, o));

    const int g = lane >> 3;
    int rank = 0;
#pragma unroll
    for (int gg = 0; gg < 8; ++gg) {
        float vg = __shfl(gm, gg * 8);
        rank += (vg > gm) || (vg == gm && gg < g);
    }
    const bool allowed = rank < TOPKG;

    float mv[4];
#pragma unroll
    for (int j = 0; j < 4; ++j) mv[j] = allowed ? l[j] : -INFINITY;

    float wsel = 0.0f;
    int   isel = 0;

    for (int k = 0; k < TOPK; ++k) {
        float bv = mv[0];
        int   bi = lane * 4;
        if (mv[1] > bv) { bv = mv[1]; bi = lane * 4 + 1; }
        if (mv[2] > bv) { bv = mv[2]; bi = lane * 4 + 2; }
        if (mv[3] > bv) { bv = mv[3]; bi = lane * 4 + 3; }
#pragma unroll
        for (int o = 32; o; o >>= 1) {
            float ov = __shfl_xor(bv, o);
            int   oi = __shfl_xor(bi, o);
            if (ov > bv || (ov == bv && oi < bi)) { bv = ov; bi = oi; }
        }
        if (lane == k) { wsel = __expf(bv - m) / s; isel = bi; }
        if ((bi >> 2) == lane) mv[bi & 3] = -INFINITY;
    }

    if (lane < TOPK) {
        outw[(size_t)tok * TOPK + lane] = wsel;
        outi[(size_t)tok * TOPK + lane] = (float)isel;
    }
}

extern "C" void kernel_launch(void* const* d_in, const int* in_sizes, int n_in,
                              void* d_out, int out_size, void* d_ws, size_t ws_size,
                              hipStream_t stream) {
    const float* x  = (const float*)d_in[0];   // [16384, 4096]
    const float* wt = (const float*)d_in[1];   // [256, 4096]

    // ws layout: partials [4][16384][256] f32 (64 MB) | Wh (2 MB) | Wl (2 MB)
    float* P = (float*)d_ws;
    unsigned short* Wh = (unsigned short*)((char*)d_ws + (size_t)NSPLIT * NTOK * NEXP * 4);
    unsigned short* Wl = Wh + (size_t)NEXP * DIM;

    float* outw = (float*)d_out;
    float* outi = (float*)d_out + (size_t)NTOK * TOPK;

    wprep<<<(NEXP * DIM) / (256 * 4), 256, 0, stream>>>(wt, Wh, Wl);

    dim3 ggrid(NTOK / BM, NSPLIT);   // (64, 4) = 256 blocks, 1/CU, 8 waves
    gate_gemm<<<ggrid, 512, 0, stream>>>(x, Wh, Wl, P);

    gate_route<<<(NTOK * 64) / 256, 256, 0, stream>>>(P, outw, outi);
}